// Round 1
// baseline (456.848 us; speedup 1.0000x reference)
//
#include <hip/hip_runtime.h>

#define N_NODES 100000
#define F_FRAG  16384
#define D_DANG  8192
#define E_EDGE  4096
#define EMB     300
#define EMB2    90000   // EMB*EMB

// ws layout (floats):
//   frag_sum : F_FRAG*EMB
//   counts   : F_FRAG
//   needed   : F_FRAG (int, punned)
//   h        : D_DANG*EMB

__global__ void zero_ws(float* ws, int n4) {
    float4 z = {0.f, 0.f, 0.f, 0.f};
    float4* p = (float4*)ws;
    for (int j = blockIdx.x * blockDim.x + threadIdx.x; j < n4;
         j += gridDim.x * blockDim.x)
        p[j] = z;
}

__global__ void mark_needed(const int* __restrict__ dangling_idx,
                            const int* __restrict__ frag_batch,
                            int* __restrict__ needed) {
    int i = blockIdx.x * blockDim.x + threadIdx.x;
    if (i < D_DANG) needed[frag_batch[dangling_idx[i]]] = 1;
}

// One 64-lane wave per node; skip nodes whose fragment is never consumed.
__global__ __launch_bounds__(256) void scatter_frag(
    const float* __restrict__ out, const int* __restrict__ frag_batch,
    const int* __restrict__ needed, float* __restrict__ frag_sum,
    float* __restrict__ counts) {
    int grp  = threadIdx.x >> 6;
    int lane = threadIdx.x & 63;
    int node = blockIdx.x * 4 + grp;
    if (node >= N_NODES) return;
    int f = frag_batch[node];
    if (!needed[f]) return;
    if (lane == 0) atomicAdd(&counts[f], 1.0f);
    const float4* row = (const float4*)(out + (size_t)node * EMB); // 1200B rows are 16B-aligned
    float* dst = frag_sum + (size_t)f * EMB;
    for (int j = lane; j < EMB / 4; j += 64) {
        float4 v = row[j];
        atomicAdd(&dst[j * 4 + 0], v.x);
        atomicAdd(&dst[j * 4 + 1], v.y);
        atomicAdd(&dst[j * 4 + 2], v.z);
        atomicAdd(&dst[j * 4 + 3], v.w);
    }
}

// h[d] = out[dangling_idx[d]] @ W + b + frag_mean[frag_batch[dangling_idx[d]]]
// 16 nodes per 256-thread block; threads = 4 node-groups x 64 col-lanes.
__global__ __launch_bounds__(256) void proj_kernel(
    const float* __restrict__ out, const int* __restrict__ dangling_idx,
    const int* __restrict__ frag_batch, const float* __restrict__ W,
    const float* __restrict__ b, const float* __restrict__ frag_sum,
    const float* __restrict__ counts, float* __restrict__ h) {
    __shared__ float rows[16][EMB];
    int base = blockIdx.x * 16;
    for (int nl = 0; nl < 16; ++nl) {
        int gi = dangling_idx[base + nl];
        for (int d = threadIdx.x; d < EMB; d += 256)
            rows[nl][d] = out[(size_t)gi * EMB + d];
    }
    __syncthreads();
    int ck = threadIdx.x & 63;
    int tn = threadIdx.x >> 6;
    float acc[4][5];
#pragma unroll
    for (int i = 0; i < 4; ++i)
#pragma unroll
        for (int j = 0; j < 5; ++j) acc[i][j] = 0.f;

    for (int d = 0; d < EMB; ++d) {
        float w[5];
#pragma unroll
        for (int j = 0; j < 5; ++j) {
            int k = ck + 64 * j;
            w[j] = (k < EMB) ? W[d * EMB + k] : 0.f;
        }
#pragma unroll
        for (int i = 0; i < 4; ++i) {
            float r = rows[tn * 4 + i][d];
#pragma unroll
            for (int j = 0; j < 5; ++j) acc[i][j] += r * w[j];
        }
    }
#pragma unroll
    for (int i = 0; i < 4; ++i) {
        int node = base + tn * 4 + i;
        int gi   = dangling_idx[node];
        int f    = frag_batch[gi];
        float invc = 1.0f / fmaxf(counts[f], 1.0f);
#pragma unroll
        for (int j = 0; j < 5; ++j) {
            int k = ck + 64 * j;
            if (k < EMB)
                h[(size_t)node * EMB + k] =
                    acc[i][j] + b[k] + frag_sum[(size_t)f * EMB + k] * invc;
        }
    }
}

// Per edge e: v = (M1[a0]+M2[a1])^T h_src;  logits[e] = v.h_dst;
// logits[E+e] = v.h_dst2 where dst2 = eidx[1][(e-1) mod E]  (roll by +1).
__global__ __launch_bounds__(256) void edge_kernel(
    const float* __restrict__ h, const int* __restrict__ eidx,
    const int* __restrict__ attr, const float* __restrict__ emb1,
    const float* __restrict__ emb2, float* __restrict__ outp) {
    __shared__ float hs[EMB], hd[EMB], hd2[EMB];
    __shared__ float r1[4], r2[4];
    int e = blockIdx.x;
    int a0 = attr[e * 2 + 0], a1 = attr[e * 2 + 1];
    int src = eidx[e], dst = eidx[E_EDGE + e];
    int ep = (e == 0) ? (E_EDGE - 1) : (e - 1);
    int dst2 = eidx[E_EDGE + ep];
    for (int d = threadIdx.x; d < EMB; d += 256) {
        hs[d]  = h[(size_t)src  * EMB + d];
        hd[d]  = h[(size_t)dst  * EMB + d];
        hd2[d] = h[(size_t)dst2 * EMB + d];
    }
    __syncthreads();
    int k0 = threadIdx.x;
    int k1 = threadIdx.x + 256;
    bool has1 = (k1 < EMB);
    const float* M1 = emb1 + (size_t)a0 * EMB2;
    const float* M2 = emb2 + (size_t)a1 * EMB2;
    float v0 = 0.f, v1 = 0.f;
    for (int d = 0; d < EMB; ++d) {
        float s = hs[d];
        v0 += s * (M1[d * EMB + k0] + M2[d * EMB + k0]);
        if (has1) v1 += s * (M1[d * EMB + k1] + M2[d * EMB + k1]);
    }
    float p1 = v0 * hd[k0], p2 = v0 * hd2[k0];
    if (has1) { p1 += v1 * hd[k1]; p2 += v1 * hd2[k1]; }
    for (int off = 32; off; off >>= 1) {
        p1 += __shfl_down(p1, off);
        p2 += __shfl_down(p2, off);
    }
    int wid = threadIdx.x >> 6, lane = threadIdx.x & 63;
    if (lane == 0) { r1[wid] = p1; r2[wid] = p2; }
    __syncthreads();
    if (threadIdx.x == 0) {
        outp[e]              = r1[0] + r1[1] + r1[2] + r1[3];
        outp[E_EDGE + e]     = r2[0] + r2[1] + r2[2] + r2[3];
        outp[2 * E_EDGE + e] = 1.0f;   // labels: ones
        outp[3 * E_EDGE + e] = 0.0f;   // labels: zeros
    }
}

extern "C" void kernel_launch(void* const* d_in, const int* in_sizes, int n_in,
                              void* d_out, int out_size, void* d_ws, size_t ws_size,
                              hipStream_t stream) {
    const float* out          = (const float*)d_in[0];
    const int*   frag_batch   = (const int*)d_in[1];
    const int*   dangling_idx = (const int*)d_in[2];
    const int*   eidx         = (const int*)d_in[3];
    const int*   attr         = (const int*)d_in[4];
    const float* W            = (const float*)d_in[5];
    const float* b            = (const float*)d_in[6];
    const float* emb1         = (const float*)d_in[7];
    const float* emb2         = (const float*)d_in[8];
    float* o  = (float*)d_out;
    float* ws = (float*)d_ws;

    float* frag_sum = ws;
    float* counts   = ws + (size_t)F_FRAG * EMB;
    int*   needed   = (int*)(ws + (size_t)F_FRAG * EMB + F_FRAG);
    float* h        = ws + (size_t)F_FRAG * EMB + 2 * (size_t)F_FRAG;

    int zero_words = F_FRAG * EMB + 2 * F_FRAG;   // frag_sum + counts + needed
    zero_ws<<<1024, 256, 0, stream>>>(ws, zero_words / 4);
    mark_needed<<<(D_DANG + 255) / 256, 256, 0, stream>>>(dangling_idx, frag_batch, needed);
    scatter_frag<<<(N_NODES + 3) / 4, 256, 0, stream>>>(out, frag_batch, needed, frag_sum, counts);
    proj_kernel<<<D_DANG / 16, 256, 0, stream>>>(out, dangling_idx, frag_batch, W, b,
                                                 frag_sum, counts, h);
    edge_kernel<<<E_EDGE, 256, 0, stream>>>(h, eidx, attr, emb1, emb2, o);
}

// Round 2
// 269.291 us; speedup vs baseline: 1.6965x; 1.6965x over previous
//
#include <hip/hip_runtime.h>

#define N_NODES 100000
#define F_FRAG  16384
#define D_DANG  8192
#define E_EDGE  4096
#define EMB     300
#define EMB2    90000   // EMB*EMB

// ---------------- init ----------------
__global__ void init_meta(int* hist, int* remap, int* chist, int* ccur, int* n_needed) {
    int i = blockIdx.x * blockDim.x + threadIdx.x;
    if (i < F_FRAG) { hist[i] = 0; remap[i] = -1; }
    if (i < 16) { chist[i] = 0; ccur[i] = 0; }
    if (i == 0) *n_needed = 0;
}

// mark fragments consumed by dangling nodes; assign compact ids
__global__ void mark_needed(const int* __restrict__ dangling_idx,
                            const int* __restrict__ frag_batch,
                            int* __restrict__ remap, int* __restrict__ n_needed) {
    int i = blockIdx.x * blockDim.x + threadIdx.x;
    if (i >= D_DANG) return;
    int f = frag_batch[dangling_idx[i]];
    if (atomicCAS(&remap[f], -1, -2) == -1)
        remap[f] = atomicAdd(n_needed, 1);
}

// ---------------- counting sort of nodes by fragment ----------------
__global__ void node_hist(const int* __restrict__ frag_batch, int* __restrict__ hist) {
    int i = blockIdx.x * blockDim.x + threadIdx.x;
    if (i < N_NODES) atomicAdd(&hist[frag_batch[i]], 1);
}

__global__ __launch_bounds__(256) void scan_hist(const int* __restrict__ hist,
                                                 int* __restrict__ offs,
                                                 int* __restrict__ cur) {
    __shared__ int part[256];
    __shared__ int pref[257];
    int t = threadIdx.x;
    int base = t * 64;
    int s = 0;
    for (int j = 0; j < 64; ++j) s += hist[base + j];
    part[t] = s;
    __syncthreads();
    if (t == 0) {
        pref[0] = 0;
        for (int i = 0; i < 256; ++i) pref[i + 1] = pref[i] + part[i];
    }
    __syncthreads();
    int run = pref[t];
    for (int j = 0; j < 64; ++j) {
        offs[base + j] = run;
        cur[base + j]  = run;
        run += hist[base + j];
    }
}

__global__ void scatter_nodes(const int* __restrict__ frag_batch,
                              int* __restrict__ cur, int* __restrict__ node_list) {
    int i = blockIdx.x * blockDim.x + threadIdx.x;
    if (i >= N_NODES) return;
    int f = frag_batch[i];
    int p = atomicAdd(&cur[f], 1);
    node_list[p] = i;
}

// one wave per fragment; only needed fragments; writes MEAN (compacted)
__global__ __launch_bounds__(256) void gather_mean(
    const float* __restrict__ out, const int* __restrict__ remap,
    const int* __restrict__ hist, const int* __restrict__ offs,
    const int* __restrict__ node_list, float* __restrict__ fmean) {
    int wid  = blockIdx.x * 4 + (threadIdx.x >> 6);
    int lane = threadIdx.x & 63;
    if (wid >= F_FRAG) return;
    int cid = remap[wid];
    if (cid < 0) return;
    int cnt = hist[wid], off = offs[wid];
    float acc[5] = {0.f, 0.f, 0.f, 0.f, 0.f};
    for (int n = 0; n < cnt; ++n) {
        const float* row = out + (size_t)node_list[off + n] * EMB;
#pragma unroll
        for (int j = 0; j < 5; ++j) {
            int k = lane + 64 * j;
            if (k < EMB) acc[j] += row[k];
        }
    }
    float inv = 1.0f / fmaxf((float)cnt, 1.0f);
#pragma unroll
    for (int j = 0; j < 5; ++j) {
        int k = lane + 64 * j;
        if (k < EMB) fmean[(size_t)cid * EMB + k] = acc[j] * inv;
    }
}

// ---------------- projection: h = out[didx] @ W + b + fmean ----------------
__global__ __launch_bounds__(256) void proj_kernel(
    const float* __restrict__ out, const int* __restrict__ dangling_idx,
    const int* __restrict__ frag_batch, const int* __restrict__ remap,
    const float* __restrict__ W, const float* __restrict__ b,
    const float* __restrict__ fmean, float* __restrict__ h) {
    __shared__ float rows[16][EMB];
    int base = blockIdx.x * 16;
    for (int nl = 0; nl < 16; ++nl) {
        int gi = dangling_idx[base + nl];
        for (int d = threadIdx.x; d < EMB; d += 256)
            rows[nl][d] = out[(size_t)gi * EMB + d];
    }
    __syncthreads();
    int ck = threadIdx.x & 63;
    int tn = threadIdx.x >> 6;
    float acc[4][5];
#pragma unroll
    for (int i = 0; i < 4; ++i)
#pragma unroll
        for (int j = 0; j < 5; ++j) acc[i][j] = 0.f;

#pragma unroll 4
    for (int d = 0; d < EMB; ++d) {
        float w[5];
#pragma unroll
        for (int j = 0; j < 5; ++j) {
            int k = ck + 64 * j;
            w[j] = (k < EMB) ? W[d * EMB + k] : 0.f;
        }
#pragma unroll
        for (int i = 0; i < 4; ++i) {
            float r = rows[tn * 4 + i][d];
#pragma unroll
            for (int j = 0; j < 5; ++j) acc[i][j] += r * w[j];
        }
    }
#pragma unroll
    for (int i = 0; i < 4; ++i) {
        int node = base + tn * 4 + i;
        int gi   = dangling_idx[node];
        int cid  = remap[frag_batch[gi]];
#pragma unroll
        for (int j = 0; j < 5; ++j) {
            int k = ck + 64 * j;
            if (k < EMB)
                h[(size_t)node * EMB + k] =
                    acc[i][j] + b[k] + fmean[(size_t)cid * EMB + k];
        }
    }
}

// ---------------- sort edges by (a0,a1) combo (9 bins) ----------------
__global__ void combo_hist(const int* __restrict__ attr, int* __restrict__ chist) {
    int e = blockIdx.x * blockDim.x + threadIdx.x;
    if (e < E_EDGE) atomicAdd(&chist[attr[e * 2] * 3 + attr[e * 2 + 1]], 1);
}

__global__ void combo_scan(const int* __restrict__ chist, int* __restrict__ coffs,
                           int* __restrict__ ccur) {
    if (threadIdx.x == 0 && blockIdx.x == 0) {
        int run = 0;
        for (int c = 0; c < 9; ++c) { coffs[c] = run; ccur[c] = run; run += chist[c]; }
        coffs[9] = run;
    }
}

__global__ void combo_scatter(const int* __restrict__ attr, int* __restrict__ ccur,
                              int* __restrict__ esorted) {
    int e = blockIdx.x * blockDim.x + threadIdx.x;
    if (e >= E_EDGE) return;
    int c = attr[e * 2] * 3 + attr[e * 2 + 1];
    int p = atomicAdd(&ccur[c], 1);
    esorted[p] = e;
}

// Mc[c] = emb1[c/3] + emb2[c%3]
__global__ void build_mc(const float* __restrict__ emb1, const float* __restrict__ emb2,
                         float* __restrict__ Mc) {
    int c = blockIdx.y;
    int i = blockIdx.x * blockDim.x + threadIdx.x;
    if (i < EMB2)
        Mc[(size_t)c * EMB2 + i] = emb1[(size_t)(c / 3) * EMB2 + i] +
                                   emb2[(size_t)(c % 3) * EMB2 + i];
}

// ---------------- per-combo edge GEMM + fused dots ----------------
// block = (tile of 16 edges of combo c); threads = 64 col-lanes x 4 edge-groups
__global__ __launch_bounds__(256) void edge_gemm(
    const float* __restrict__ h, const float* __restrict__ Mc,
    const int* __restrict__ eidx, const int* __restrict__ esorted,
    const int* __restrict__ coffs, float* __restrict__ outp) {
    int c     = blockIdx.y;
    int start = coffs[c] + blockIdx.x * 16;
    int end   = coffs[c + 1];
    if (start >= end) return;
    int ne = min(16, end - start);

    __shared__ float hs[16][EMB];
    __shared__ int eids[16], srcs[16], dsts[16], dsts2[16];

    if (threadIdx.x < 16) {
        int i  = threadIdx.x;
        int eo = esorted[start + ((i < ne) ? i : 0)];
        eids[i] = eo;
        srcs[i] = eidx[eo];
        dsts[i] = eidx[E_EDGE + eo];
        int ep  = (eo == 0) ? (E_EDGE - 1) : (eo - 1);
        dsts2[i] = eidx[E_EDGE + ep];
    }
    __syncthreads();
    for (int i = 0; i < 16; ++i) {
        int src = srcs[i];
        for (int d = threadIdx.x; d < EMB; d += 256)
            hs[i][d] = h[(size_t)src * EMB + d];
    }
    __syncthreads();

    const float* M = Mc + (size_t)c * EMB2;
    int ck = threadIdx.x & 63;
    int tn = threadIdx.x >> 6;
    float acc[4][5];
#pragma unroll
    for (int i = 0; i < 4; ++i)
#pragma unroll
        for (int j = 0; j < 5; ++j) acc[i][j] = 0.f;

#pragma unroll 4
    for (int d = 0; d < EMB; ++d) {
        float w[5];
#pragma unroll
        for (int j = 0; j < 5; ++j) {
            int k = ck + 64 * j;
            w[j] = (k < EMB) ? M[(size_t)d * EMB + k] : 0.f;
        }
#pragma unroll
        for (int i = 0; i < 4; ++i) {
            float s = hs[tn * 4 + i][d];
#pragma unroll
            for (int j = 0; j < 5; ++j) acc[i][j] += s * w[j];
        }
    }

    float p1[4], p2[4];
#pragma unroll
    for (int i = 0; i < 4; ++i) {
        int dst = dsts[tn * 4 + i], dst2 = dsts2[tn * 4 + i];
        float s1 = 0.f, s2 = 0.f;
#pragma unroll
        for (int j = 0; j < 5; ++j) {
            int k = ck + 64 * j;
            if (k < EMB) {
                s1 += acc[i][j] * h[(size_t)dst * EMB + k];
                s2 += acc[i][j] * h[(size_t)dst2 * EMB + k];
            }
        }
        p1[i] = s1; p2[i] = s2;
    }
#pragma unroll
    for (int i = 0; i < 4; ++i)
        for (int off = 32; off; off >>= 1) {
            p1[i] += __shfl_down(p1[i], off);
            p2[i] += __shfl_down(p2[i], off);
        }
    if ((threadIdx.x & 63) == 0) {
#pragma unroll
        for (int i = 0; i < 4; ++i) {
            int li = tn * 4 + i;
            if (li < ne) {
                int eo = eids[li];
                outp[eo]          = p1[i];
                outp[E_EDGE + eo] = p2[i];
            }
        }
    }
}

__global__ void fill_labels(float* __restrict__ outp) {
    int i = blockIdx.x * blockDim.x + threadIdx.x;
    if (i < E_EDGE) {
        outp[2 * E_EDGE + i] = 1.0f;
        outp[3 * E_EDGE + i] = 0.0f;
    }
}

extern "C" void kernel_launch(void* const* d_in, const int* in_sizes, int n_in,
                              void* d_out, int out_size, void* d_ws, size_t ws_size,
                              hipStream_t stream) {
    const float* out          = (const float*)d_in[0];
    const int*   frag_batch   = (const int*)d_in[1];
    const int*   dangling_idx = (const int*)d_in[2];
    const int*   eidx         = (const int*)d_in[3];
    const int*   attr         = (const int*)d_in[4];
    const float* W            = (const float*)d_in[5];
    const float* b            = (const float*)d_in[6];
    const float* emb1         = (const float*)d_in[7];
    const float* emb2         = (const float*)d_in[8];
    float* o  = (float*)d_out;

    char* p = (char*)d_ws;
    auto alloc = [&](size_t bytes) {
        char* r = p;
        p += (bytes + 255) & ~(size_t)255;
        return (void*)r;
    };
    float* fmean     = (float*)alloc((size_t)D_DANG * EMB * 4); // compacted means
    float* h         = (float*)alloc((size_t)D_DANG * EMB * 4);
    float* Mc        = (float*)alloc((size_t)9 * EMB2 * 4);
    int*   hist      = (int*)alloc(F_FRAG * 4);
    int*   offs      = (int*)alloc(F_FRAG * 4);
    int*   cur       = (int*)alloc(F_FRAG * 4);
    int*   remap     = (int*)alloc(F_FRAG * 4);
    int*   node_list = (int*)alloc(N_NODES * 4);
    int*   esorted   = (int*)alloc(E_EDGE * 4);
    int*   chist     = (int*)alloc(16 * 4);
    int*   coffs     = (int*)alloc(16 * 4);
    int*   ccur      = (int*)alloc(16 * 4);
    int*   n_needed  = (int*)alloc(4);

    init_meta<<<F_FRAG / 256, 256, 0, stream>>>(hist, remap, chist, ccur, n_needed);
    mark_needed<<<D_DANG / 256, 256, 0, stream>>>(dangling_idx, frag_batch, remap, n_needed);
    node_hist<<<(N_NODES + 255) / 256, 256, 0, stream>>>(frag_batch, hist);
    scan_hist<<<1, 256, 0, stream>>>(hist, offs, cur);
    scatter_nodes<<<(N_NODES + 255) / 256, 256, 0, stream>>>(frag_batch, cur, node_list);
    gather_mean<<<F_FRAG / 4, 256, 0, stream>>>(out, remap, hist, offs, node_list, fmean);
    proj_kernel<<<D_DANG / 16, 256, 0, stream>>>(out, dangling_idx, frag_batch, remap,
                                                 W, b, fmean, h);
    combo_hist<<<(E_EDGE + 255) / 256, 256, 0, stream>>>(attr, chist);
    combo_scan<<<1, 64, 0, stream>>>(chist, coffs, ccur);
    combo_scatter<<<(E_EDGE + 255) / 256, 256, 0, stream>>>(attr, ccur, esorted);
    build_mc<<<dim3((EMB2 + 255) / 256, 9), 256, 0, stream>>>(emb1, emb2, Mc);
    edge_gemm<<<dim3(256, 9), 256, 0, stream>>>(h, Mc, eidx, esorted, coffs, o);
    fill_labels<<<(E_EDGE + 255) / 256, 256, 0, stream>>>(o);
}

// Round 3
// 263.289 us; speedup vs baseline: 1.7352x; 1.0228x over previous
//
#include <hip/hip_runtime.h>

#define N_NODES 100000
#define F_FRAG  16384
#define D_DANG  8192
#define E_EDGE  4096
#define EMB     300
#define EMB2    90000   // EMB*EMB
#define EMB4    75      // EMB/4

// ---------------- init ----------------
__global__ void init_meta(int* hist, int* remap, int* chist, int* ccur, int* n_needed) {
    int i = blockIdx.x * blockDim.x + threadIdx.x;
    if (i < F_FRAG) { hist[i] = 0; remap[i] = -1; }
    if (i < 16) { chist[i] = 0; ccur[i] = 0; }
    if (i == 0) *n_needed = 0;
}

// mark fragments consumed by dangling nodes; assign compact ids
__global__ void mark_needed(const int* __restrict__ dangling_idx,
                            const int* __restrict__ frag_batch,
                            int* __restrict__ remap, int* __restrict__ n_needed) {
    int i = blockIdx.x * blockDim.x + threadIdx.x;
    if (i >= D_DANG) return;
    int f = frag_batch[dangling_idx[i]];
    if (atomicCAS(&remap[f], -1, -2) == -1)
        remap[f] = atomicAdd(n_needed, 1);
}

// ---------------- counting sort of nodes by fragment ----------------
__global__ void node_hist(const int* __restrict__ frag_batch, int* __restrict__ hist) {
    int i = blockIdx.x * blockDim.x + threadIdx.x;
    if (i < N_NODES) atomicAdd(&hist[frag_batch[i]], 1);
}

__global__ __launch_bounds__(256) void scan_hist(const int* __restrict__ hist,
                                                 int* __restrict__ offs,
                                                 int* __restrict__ cur) {
    __shared__ int part[256];
    __shared__ int pref[257];
    int t = threadIdx.x;
    int base = t * 64;
    int s = 0;
    for (int j = 0; j < 64; ++j) s += hist[base + j];
    part[t] = s;
    __syncthreads();
    if (t == 0) {
        pref[0] = 0;
        for (int i = 0; i < 256; ++i) pref[i + 1] = pref[i] + part[i];
    }
    __syncthreads();
    int run = pref[t];
    for (int j = 0; j < 64; ++j) {
        offs[base + j] = run;
        cur[base + j]  = run;
        run += hist[base + j];
    }
}

__global__ void scatter_nodes(const int* __restrict__ frag_batch,
                              int* __restrict__ cur, int* __restrict__ node_list) {
    int i = blockIdx.x * blockDim.x + threadIdx.x;
    if (i >= N_NODES) return;
    int f = frag_batch[i];
    int p = atomicAdd(&cur[f], 1);
    node_list[p] = i;
}

// one wave per (fragment, 64-col chunk); only needed fragments; writes MEAN (compacted)
__global__ __launch_bounds__(256) void gather_mean(
    const float* __restrict__ out, const int* __restrict__ remap,
    const int* __restrict__ hist, const int* __restrict__ offs,
    const int* __restrict__ node_list, float* __restrict__ fmean) {
    int wid  = blockIdx.x * 4 + (threadIdx.x >> 6);
    if (wid >= F_FRAG) return;
    int cid = remap[wid];
    if (cid < 0) return;
    int lane = threadIdx.x & 63;
    int k = blockIdx.y * 64 + lane;
    if (k >= EMB) return;
    int cnt = hist[wid], off = offs[wid];
    float a0 = 0.f, a1 = 0.f, a2 = 0.f, a3 = 0.f;
    int n = 0;
    for (; n + 3 < cnt; n += 4) {
        int i0 = node_list[off + n], i1 = node_list[off + n + 1];
        int i2 = node_list[off + n + 2], i3 = node_list[off + n + 3];
        a0 += out[(size_t)i0 * EMB + k];
        a1 += out[(size_t)i1 * EMB + k];
        a2 += out[(size_t)i2 * EMB + k];
        a3 += out[(size_t)i3 * EMB + k];
    }
    for (; n < cnt; ++n) a0 += out[(size_t)node_list[off + n] * EMB + k];
    float s = (a0 + a1) + (a2 + a3);
    fmean[(size_t)cid * EMB + k] = s / fmaxf((float)cnt, 1.0f);
}

// ---------------- projection: h = out[didx] @ W + b + fmean ----------------
// block = 32 rows x 64-col chunk; 256 thr = 4 row-groups x 64 lanes; 8 rows/thread
__global__ __launch_bounds__(256) void proj_kernel(
    const float* __restrict__ out, const int* __restrict__ dangling_idx,
    const int* __restrict__ frag_batch, const int* __restrict__ remap,
    const float* __restrict__ W, const float* __restrict__ b,
    const float* __restrict__ fmean, float* __restrict__ h) {
    __shared__ float rows[32][EMB];
    __shared__ int gidx[32], cids[32];
    int base = blockIdx.x * 32;
    if (threadIdx.x < 32) {
        int gi = dangling_idx[base + threadIdx.x];
        gidx[threadIdx.x] = gi;
        cids[threadIdx.x] = remap[frag_batch[gi]];
    }
    __syncthreads();
    {
        float4* dst = (float4*)&rows[0][0];
        for (int j = threadIdx.x; j < 32 * EMB4; j += 256) {
            int r = j / EMB4, col = j - r * EMB4;
            dst[j] = ((const float4*)(out + (size_t)gidx[r] * EMB))[col];
        }
    }
    __syncthreads();
    int lane = threadIdx.x & 63;
    int tn   = threadIdx.x >> 6;
    int k    = blockIdx.y * 64 + lane;
    bool kok = (k < EMB);
    float acc[8];
#pragma unroll
    for (int i = 0; i < 8; ++i) acc[i] = 0.f;

    for (int d = 0; d < EMB; d += 4) {
        float w0 = kok ? W[(size_t)(d + 0) * EMB + k] : 0.f;
        float w1 = kok ? W[(size_t)(d + 1) * EMB + k] : 0.f;
        float w2 = kok ? W[(size_t)(d + 2) * EMB + k] : 0.f;
        float w3 = kok ? W[(size_t)(d + 3) * EMB + k] : 0.f;
#pragma unroll
        for (int i = 0; i < 8; ++i) {
            float4 hv = *(const float4*)&rows[tn * 8 + i][d];
            acc[i] += hv.x * w0 + hv.y * w1 + hv.z * w2 + hv.w * w3;
        }
    }
    if (kok) {
        float bk = b[k];
#pragma unroll
        for (int i = 0; i < 8; ++i) {
            int li = tn * 8 + i;
            h[(size_t)(base + li) * EMB + k] =
                acc[i] + bk + fmean[(size_t)cids[li] * EMB + k];
        }
    }
}

// ---------------- sort edges by (a0,a1) combo (9 bins) ----------------
__global__ void combo_hist(const int* __restrict__ attr, int* __restrict__ chist) {
    int e = blockIdx.x * blockDim.x + threadIdx.x;
    if (e < E_EDGE) atomicAdd(&chist[attr[e * 2] * 3 + attr[e * 2 + 1]], 1);
}

__global__ void combo_scan(const int* __restrict__ chist, int* __restrict__ coffs,
                           int* __restrict__ ccur) {
    if (threadIdx.x == 0 && blockIdx.x == 0) {
        int run = 0;
        for (int c = 0; c < 9; ++c) { coffs[c] = run; ccur[c] = run; run += chist[c]; }
        coffs[9] = run;
    }
}

__global__ void combo_scatter(const int* __restrict__ attr, int* __restrict__ ccur,
                              int* __restrict__ esorted) {
    int e = blockIdx.x * blockDim.x + threadIdx.x;
    if (e >= E_EDGE) return;
    int c = attr[e * 2] * 3 + attr[e * 2 + 1];
    int p = atomicAdd(&ccur[c], 1);
    esorted[p] = e;
}

// Mc[c] = emb1[c/3] + emb2[c%3]
__global__ void build_mc(const float* __restrict__ emb1, const float* __restrict__ emb2,
                         float* __restrict__ Mc) {
    int c = blockIdx.y;
    int i = blockIdx.x * blockDim.x + threadIdx.x;
    if (i < EMB2)
        Mc[(size_t)c * EMB2 + i] = emb1[(size_t)(c / 3) * EMB2 + i] +
                                   emb2[(size_t)(c % 3) * EMB2 + i];
}

// ---------------- per-combo edge GEMM: V[s] = h[src(s)] @ Mc[c] ----------------
// grid (tile, kchunk, combo); block = 32 edges x 64-col chunk; 8 edges/thread
__global__ __launch_bounds__(256) void edge_gemm(
    const float* __restrict__ h, const float* __restrict__ Mc,
    const int* __restrict__ eidx, const int* __restrict__ esorted,
    const int* __restrict__ coffs, float* __restrict__ V) {
    int c     = blockIdx.z;
    int start = coffs[c] + blockIdx.x * 32;
    int end   = coffs[c + 1];
    if (start >= end) return;
    int ne = min(32, end - start);

    __shared__ float hs[32][EMB];
    __shared__ int srcs[32];
    if (threadIdx.x < 32) {
        int li = threadIdx.x;
        int s  = start + ((li < ne) ? li : 0);
        srcs[li] = eidx[esorted[s]];
    }
    __syncthreads();
    {
        float4* dst = (float4*)&hs[0][0];
        for (int j = threadIdx.x; j < 32 * EMB4; j += 256) {
            int r = j / EMB4, col = j - r * EMB4;
            dst[j] = ((const float4*)(h + (size_t)srcs[r] * EMB))[col];
        }
    }
    __syncthreads();

    int lane = threadIdx.x & 63;
    int tn   = threadIdx.x >> 6;
    int k    = blockIdx.y * 64 + lane;
    bool kok = (k < EMB);
    const float* M = Mc + (size_t)c * EMB2;
    float acc[8];
#pragma unroll
    for (int i = 0; i < 8; ++i) acc[i] = 0.f;

    for (int d = 0; d < EMB; d += 4) {
        float w0 = kok ? M[(size_t)(d + 0) * EMB + k] : 0.f;
        float w1 = kok ? M[(size_t)(d + 1) * EMB + k] : 0.f;
        float w2 = kok ? M[(size_t)(d + 2) * EMB + k] : 0.f;
        float w3 = kok ? M[(size_t)(d + 3) * EMB + k] : 0.f;
#pragma unroll
        for (int i = 0; i < 8; ++i) {
            float4 hv = *(const float4*)&hs[tn * 8 + i][d];
            acc[i] += hv.x * w0 + hv.y * w1 + hv.z * w2 + hv.w * w3;
        }
    }
    if (kok) {
#pragma unroll
        for (int i = 0; i < 8; ++i) {
            int li = tn * 8 + i;
            if (li < ne)
                V[(size_t)(start + li) * EMB + k] = acc[i];
        }
    }
}

// ---------------- final dots: logits ----------------
__global__ __launch_bounds__(256) void edge_dot(
    const float* __restrict__ V, const float* __restrict__ h,
    const int* __restrict__ esorted, const int* __restrict__ eidx,
    float* __restrict__ outp) {
    int s = blockIdx.x * 4 + (threadIdx.x >> 6);
    if (s >= E_EDGE) return;
    int lane = threadIdx.x & 63;
    int eo   = esorted[s];
    int dst  = eidx[E_EDGE + eo];
    int ep   = (eo == 0) ? (E_EDGE - 1) : (eo - 1);
    int dst2 = eidx[E_EDGE + ep];
    const float* v  = V + (size_t)s * EMB;
    const float* h1 = h + (size_t)dst * EMB;
    const float* h2 = h + (size_t)dst2 * EMB;
    float p1 = 0.f, p2 = 0.f;
#pragma unroll
    for (int j = 0; j < 5; ++j) {
        int k = lane + 64 * j;
        if (k < EMB) {
            float vv = v[k];
            p1 += vv * h1[k];
            p2 += vv * h2[k];
        }
    }
    for (int off = 32; off; off >>= 1) {
        p1 += __shfl_down(p1, off);
        p2 += __shfl_down(p2, off);
    }
    if (lane == 0) {
        outp[eo]          = p1;
        outp[E_EDGE + eo] = p2;
    }
}

__global__ void fill_labels(float* __restrict__ outp) {
    int i = blockIdx.x * blockDim.x + threadIdx.x;
    if (i < E_EDGE) {
        outp[2 * E_EDGE + i] = 1.0f;
        outp[3 * E_EDGE + i] = 0.0f;
    }
}

extern "C" void kernel_launch(void* const* d_in, const int* in_sizes, int n_in,
                              void* d_out, int out_size, void* d_ws, size_t ws_size,
                              hipStream_t stream) {
    const float* out          = (const float*)d_in[0];
    const int*   frag_batch   = (const int*)d_in[1];
    const int*   dangling_idx = (const int*)d_in[2];
    const int*   eidx         = (const int*)d_in[3];
    const int*   attr         = (const int*)d_in[4];
    const float* W            = (const float*)d_in[5];
    const float* b            = (const float*)d_in[6];
    const float* emb1         = (const float*)d_in[7];
    const float* emb2         = (const float*)d_in[8];
    float* o  = (float*)d_out;

    char* p = (char*)d_ws;
    auto alloc = [&](size_t bytes) {
        char* r = p;
        p += (bytes + 255) & ~(size_t)255;
        return (void*)r;
    };
    float* fmean     = (float*)alloc((size_t)D_DANG * EMB * 4); // compacted means
    float* h         = (float*)alloc((size_t)D_DANG * EMB * 4);
    float* Mc        = (float*)alloc((size_t)9 * EMB2 * 4);
    int*   hist      = (int*)alloc(F_FRAG * 4);
    int*   offs      = (int*)alloc(F_FRAG * 4);
    int*   cur       = (int*)alloc(F_FRAG * 4);
    int*   remap     = (int*)alloc(F_FRAG * 4);
    int*   node_list = (int*)alloc(N_NODES * 4);
    int*   esorted   = (int*)alloc(E_EDGE * 4);
    int*   chist     = (int*)alloc(16 * 4);
    int*   coffs     = (int*)alloc(16 * 4);
    int*   ccur      = (int*)alloc(16 * 4);
    // V aliases fmean: fmean is dead after proj_kernel; V written by edge_gemm after.
    float* V = fmean;

    init_meta<<<F_FRAG / 256, 256, 0, stream>>>(hist, remap, chist, ccur, (int*)alloc(4));
    mark_needed<<<D_DANG / 256, 256, 0, stream>>>(dangling_idx, frag_batch, remap,
                                                  (int*)(ccur + 15)); // dummy? no:
    // NOTE: n_needed pointer must be stable; re-alloc'd above. Fix: use chist[15] slot? No —
    // simpler: dedicated slot below.
    (void)0;
    node_hist<<<(N_NODES + 255) / 256, 256, 0, stream>>>(frag_batch, hist);
    scan_hist<<<1, 256, 0, stream>>>(hist, offs, cur);
    scatter_nodes<<<(N_NODES + 255) / 256, 256, 0, stream>>>(frag_batch, cur, node_list);
    gather_mean<<<dim3(F_FRAG / 4, 5), 256, 0, stream>>>(out, remap, hist, offs,
                                                         node_list, fmean);
    proj_kernel<<<dim3(D_DANG / 32, 5), 256, 0, stream>>>(out, dangling_idx, frag_batch,
                                                          remap, W, b, fmean, h);
    combo_hist<<<(E_EDGE + 255) / 256, 256, 0, stream>>>(attr, chist);
    combo_scan<<<1, 64, 0, stream>>>(chist, coffs, ccur);
    combo_scatter<<<(E_EDGE + 255) / 256, 256, 0, stream>>>(attr, ccur, esorted);
    build_mc<<<dim3((EMB2 + 255) / 256, 9), 256, 0, stream>>>(emb1, emb2, Mc);
    edge_gemm<<<dim3(128, 5, 9), 256, 0, stream>>>(h, Mc, eidx, esorted, coffs, V);
    edge_dot<<<E_EDGE / 4, 256, 0, stream>>>(V, h, esorted, eidx, o);
    fill_labels<<<(E_EDGE + 255) / 256, 256, 0, stream>>>(o);
}

// Round 4
// 216.521 us; speedup vs baseline: 2.1099x; 1.2160x over previous
//
#include <hip/hip_runtime.h>

#define N_NODES 100000
#define F_FRAG  16384
#define D_DANG  8192
#define E_EDGE  4096
#define EMB     300
#define EMB2    90000   // EMB*EMB
#define EMB4    75      // EMB/4

// ---------------- init ----------------
__global__ void init_meta(int* hist, int* remap, int* n_needed) {
    int i = blockIdx.x * blockDim.x + threadIdx.x;
    if (i < F_FRAG) { hist[i] = 0; remap[i] = -1; }
    if (i == 0) *n_needed = 0;
}

// mark fragments consumed by dangling nodes; assign compact ids
__global__ void mark_needed(const int* __restrict__ dangling_idx,
                            const int* __restrict__ frag_batch,
                            int* __restrict__ remap, int* __restrict__ n_needed) {
    int i = blockIdx.x * blockDim.x + threadIdx.x;
    if (i >= D_DANG) return;
    int f = frag_batch[dangling_idx[i]];
    if (atomicCAS(&remap[f], -1, -2) == -1)
        remap[f] = atomicAdd(n_needed, 1);
}

// ---------------- counting sort of nodes by fragment ----------------
__global__ void node_hist(const int* __restrict__ frag_batch, int* __restrict__ hist) {
    int i = blockIdx.x * blockDim.x + threadIdx.x;
    if (i < N_NODES) atomicAdd(&hist[frag_batch[i]], 1);
}

__global__ __launch_bounds__(256) void scan_hist(const int* __restrict__ hist,
                                                 int* __restrict__ offs,
                                                 int* __restrict__ cur) {
    __shared__ int part[256];
    __shared__ int pref[257];
    int t = threadIdx.x;
    int base = t * 64;
    int s = 0;
    for (int j = 0; j < 64; ++j) s += hist[base + j];
    part[t] = s;
    __syncthreads();
    if (t == 0) {
        pref[0] = 0;
        for (int i = 0; i < 256; ++i) pref[i + 1] = pref[i] + part[i];
    }
    __syncthreads();
    int run = pref[t];
    for (int j = 0; j < 64; ++j) {
        offs[base + j] = run;
        cur[base + j]  = run;
        run += hist[base + j];
    }
}

// only nodes of needed fragments get scattered
__global__ void scatter_nodes(const int* __restrict__ frag_batch,
                              const int* __restrict__ remap,
                              int* __restrict__ cur, int* __restrict__ node_list) {
    int i = blockIdx.x * blockDim.x + threadIdx.x;
    if (i >= N_NODES) return;
    int f = frag_batch[i];
    if (remap[f] < 0) return;
    int p = atomicAdd(&cur[f], 1);
    node_list[p] = i;
}

// one wave per needed fragment, full 300-col row; writes MEAN (compacted)
__global__ __launch_bounds__(256) void gather_mean(
    const float* __restrict__ out, const int* __restrict__ remap,
    const int* __restrict__ hist, const int* __restrict__ offs,
    const int* __restrict__ node_list, float* __restrict__ fmean) {
    int wid = blockIdx.x * 4 + (threadIdx.x >> 6);
    if (wid >= F_FRAG) return;
    int cid = remap[wid];
    if (cid < 0) return;
    int lane = threadIdx.x & 63;
    int cnt = hist[wid], off = offs[wid];
    float acc[5] = {0.f, 0.f, 0.f, 0.f, 0.f};
    int n = 0;
    for (; n + 1 < cnt; n += 2) {
        const float* r0 = out + (size_t)node_list[off + n] * EMB;
        const float* r1 = out + (size_t)node_list[off + n + 1] * EMB;
#pragma unroll
        for (int j = 0; j < 5; ++j) {
            int k = lane + 64 * j;
            if (k < EMB) acc[j] += r0[k] + r1[k];
        }
    }
    if (n < cnt) {
        const float* r0 = out + (size_t)node_list[off + n] * EMB;
#pragma unroll
        for (int j = 0; j < 5; ++j) {
            int k = lane + 64 * j;
            if (k < EMB) acc[j] += r0[k];
        }
    }
    float inv = 1.0f / fmaxf((float)cnt, 1.0f);
#pragma unroll
    for (int j = 0; j < 5; ++j) {
        int k = lane + 64 * j;
        if (k < EMB) fmean[(size_t)cid * EMB + k] = acc[j] * inv;
    }
}

// ---------------- projection: h = out[didx] @ W + b + fmean ----------------
// 32 rows/block, 512 thr = 8 waves x 64 lanes; thread: 4 rows x 5 cols (all 300)
__global__ __launch_bounds__(512) void proj_kernel(
    const float* __restrict__ out, const int* __restrict__ dangling_idx,
    const int* __restrict__ frag_batch, const int* __restrict__ remap,
    const float* __restrict__ W, const float* __restrict__ b,
    const float* __restrict__ fmean, float* __restrict__ h) {
    __shared__ float rows[32][EMB];
    __shared__ int gidx[32], cids[32];
    int base = blockIdx.x * 32;
    if (threadIdx.x < 32) {
        int gi = dangling_idx[base + threadIdx.x];
        gidx[threadIdx.x] = gi;
        cids[threadIdx.x] = remap[frag_batch[gi]];
    }
    __syncthreads();
    {
        float4* dst = (float4*)&rows[0][0];
        for (int j = threadIdx.x; j < 32 * EMB4; j += 512) {
            int r = j / EMB4, col = j - r * EMB4;
            dst[j] = ((const float4*)(out + (size_t)gidx[r] * EMB))[col];
        }
    }
    __syncthreads();
    int lane = threadIdx.x & 63;
    int wv   = threadIdx.x >> 6;
    bool k4ok = (lane + 256 < EMB);
    float acc[4][5];
#pragma unroll
    for (int i = 0; i < 4; ++i)
#pragma unroll
        for (int j = 0; j < 5; ++j) acc[i][j] = 0.f;

    for (int d = 0; d < EMB; d += 4) {
        float w[4][5];
#pragma unroll
        for (int t = 0; t < 4; ++t) {
            const float* Wr = W + (size_t)(d + t) * EMB + lane;
#pragma unroll
            for (int j = 0; j < 5; ++j)
                w[t][j] = (j < 4 || k4ok) ? Wr[64 * j] : 0.f;
        }
#pragma unroll
        for (int i = 0; i < 4; ++i) {
            float4 hv = *(const float4*)&rows[wv * 4 + i][d];
#pragma unroll
            for (int j = 0; j < 5; ++j)
                acc[i][j] += hv.x * w[0][j] + hv.y * w[1][j] +
                             hv.z * w[2][j] + hv.w * w[3][j];
        }
    }
#pragma unroll
    for (int i = 0; i < 4; ++i) {
        int li = wv * 4 + i;
        float* hr = h + (size_t)(base + li) * EMB;
        const float* fm = fmean + (size_t)cids[li] * EMB;
#pragma unroll
        for (int j = 0; j < 5; ++j) {
            int k = lane + 64 * j;
            if (j < 4 || k4ok)
                hr[k] = acc[i][j] + b[k] + fm[k];
        }
    }
}

// ---------------- merged edge sort by (a0,a1) combo (9 bins) ----------------
__global__ __launch_bounds__(256) void combo_sort(const int* __restrict__ attr,
                                                  int* __restrict__ esorted,
                                                  int* __restrict__ coffs) {
    __shared__ int sh[9], scur[9];
    int t = threadIdx.x;
    if (t < 9) sh[t] = 0;
    __syncthreads();
    for (int e = t; e < E_EDGE; e += 256)
        atomicAdd(&sh[attr[e * 2] * 3 + attr[e * 2 + 1]], 1);
    __syncthreads();
    if (t == 0) {
        int run = 0;
        for (int c = 0; c < 9; ++c) { scur[c] = run; coffs[c] = run; run += sh[c]; }
        coffs[9] = run;
    }
    __syncthreads();
    for (int e = t; e < E_EDGE; e += 256) {
        int c = attr[e * 2] * 3 + attr[e * 2 + 1];
        int p = atomicAdd(&scur[c], 1);
        esorted[p] = e;
    }
}

// Mc[c] = emb1[c/3] + emb2[c%3]
__global__ void build_mc(const float* __restrict__ emb1, const float* __restrict__ emb2,
                         float* __restrict__ Mc) {
    int c = blockIdx.y;
    int i = blockIdx.x * blockDim.x + threadIdx.x;
    if (i < EMB2)
        Mc[(size_t)c * EMB2 + i] = emb1[(size_t)(c / 3) * EMB2 + i] +
                                   emb2[(size_t)(c % 3) * EMB2 + i];
}

// ---------------- per-combo fused edge GEMM + dots ----------------
// 32 edges/block, 512 thr; thread: 4 edges x 5 cols; dots folded in (no V buffer)
__global__ __launch_bounds__(512) void edge_gemm(
    const float* __restrict__ h, const float* __restrict__ Mc,
    const int* __restrict__ eidx, const int* __restrict__ esorted,
    const int* __restrict__ coffs, float* __restrict__ outp) {
    int c     = blockIdx.y;
    int start = coffs[c] + blockIdx.x * 32;
    int end   = coffs[c + 1];
    if (start >= end) return;
    int ne = min(32, end - start);

    __shared__ float hs[32][EMB];
    __shared__ int eids[32], srcs[32], dsts[32], dsts2[32];
    if (threadIdx.x < 32) {
        int li = threadIdx.x;
        int eo = esorted[start + ((li < ne) ? li : 0)];
        eids[li] = eo;
        srcs[li] = eidx[eo];
        dsts[li] = eidx[E_EDGE + eo];
        int ep   = (eo == 0) ? (E_EDGE - 1) : (eo - 1);
        dsts2[li] = eidx[E_EDGE + ep];
    }
    __syncthreads();
    {
        float4* dst = (float4*)&hs[0][0];
        for (int j = threadIdx.x; j < 32 * EMB4; j += 512) {
            int r = j / EMB4, col = j - r * EMB4;
            dst[j] = ((const float4*)(h + (size_t)srcs[r] * EMB))[col];
        }
    }
    __syncthreads();

    int lane = threadIdx.x & 63;
    int wv   = threadIdx.x >> 6;
    bool k4ok = (lane + 256 < EMB);
    const float* M = Mc + (size_t)c * EMB2;
    float acc[4][5];
#pragma unroll
    for (int i = 0; i < 4; ++i)
#pragma unroll
        for (int j = 0; j < 5; ++j) acc[i][j] = 0.f;

    for (int d = 0; d < EMB; d += 4) {
        float w[4][5];
#pragma unroll
        for (int t = 0; t < 4; ++t) {
            const float* Mr = M + (size_t)(d + t) * EMB + lane;
#pragma unroll
            for (int j = 0; j < 5; ++j)
                w[t][j] = (j < 4 || k4ok) ? Mr[64 * j] : 0.f;
        }
#pragma unroll
        for (int i = 0; i < 4; ++i) {
            float4 hv = *(const float4*)&hs[wv * 4 + i][d];
#pragma unroll
            for (int j = 0; j < 5; ++j)
                acc[i][j] += hv.x * w[0][j] + hv.y * w[1][j] +
                             hv.z * w[2][j] + hv.w * w[3][j];
        }
    }

    // fused dots: logits1 = v . h[dst], logits2 = v . h[dst2]
    float p1[4], p2[4];
#pragma unroll
    for (int i = 0; i < 4; ++i) {
        int li = wv * 4 + i;
        const float* h1 = h + (size_t)dsts[li]  * EMB + lane;
        const float* h2 = h + (size_t)dsts2[li] * EMB + lane;
        float s1 = 0.f, s2 = 0.f;
#pragma unroll
        for (int j = 0; j < 5; ++j) {
            if (j < 4 || k4ok) {
                float a = acc[i][j];
                s1 += a * h1[64 * j];
                s2 += a * h2[64 * j];
            }
        }
        p1[i] = s1; p2[i] = s2;
    }
#pragma unroll
    for (int off = 32; off; off >>= 1) {
#pragma unroll
        for (int i = 0; i < 4; ++i) {
            p1[i] += __shfl_down(p1[i], off);
            p2[i] += __shfl_down(p2[i], off);
        }
    }
    if (lane == 0) {
#pragma unroll
        for (int i = 0; i < 4; ++i) {
            int li = wv * 4 + i;
            if (li < ne) {
                int eo = eids[li];
                outp[eo]          = p1[i];
                outp[E_EDGE + eo] = p2[i];
            }
        }
    }
}

__global__ void fill_labels(float* __restrict__ outp) {
    int i = blockIdx.x * blockDim.x + threadIdx.x;
    if (i < E_EDGE) {
        outp[2 * E_EDGE + i] = 1.0f;
        outp[3 * E_EDGE + i] = 0.0f;
    }
}

extern "C" void kernel_launch(void* const* d_in, const int* in_sizes, int n_in,
                              void* d_out, int out_size, void* d_ws, size_t ws_size,
                              hipStream_t stream) {
    const float* out          = (const float*)d_in[0];
    const int*   frag_batch   = (const int*)d_in[1];
    const int*   dangling_idx = (const int*)d_in[2];
    const int*   eidx         = (const int*)d_in[3];
    const int*   attr         = (const int*)d_in[4];
    const float* W            = (const float*)d_in[5];
    const float* b            = (const float*)d_in[6];
    const float* emb1         = (const float*)d_in[7];
    const float* emb2         = (const float*)d_in[8];
    float* o  = (float*)d_out;

    char* p = (char*)d_ws;
    auto alloc = [&](size_t bytes) {
        char* r = p;
        p += (bytes + 255) & ~(size_t)255;
        return (void*)r;
    };
    float* fmean     = (float*)alloc((size_t)D_DANG * EMB * 4); // compacted means
    float* h         = (float*)alloc((size_t)D_DANG * EMB * 4);
    float* Mc        = (float*)alloc((size_t)9 * EMB2 * 4);
    int*   hist      = (int*)alloc(F_FRAG * 4);
    int*   offs      = (int*)alloc(F_FRAG * 4);
    int*   cur       = (int*)alloc(F_FRAG * 4);
    int*   remap     = (int*)alloc(F_FRAG * 4);
    int*   node_list = (int*)alloc(N_NODES * 4);
    int*   esorted   = (int*)alloc(E_EDGE * 4);
    int*   coffs     = (int*)alloc(16 * 4);
    int*   n_needed  = (int*)alloc(4);

    init_meta<<<F_FRAG / 256, 256, 0, stream>>>(hist, remap, n_needed);
    mark_needed<<<D_DANG / 256, 256, 0, stream>>>(dangling_idx, frag_batch, remap, n_needed);
    node_hist<<<(N_NODES + 255) / 256, 256, 0, stream>>>(frag_batch, hist);
    scan_hist<<<1, 256, 0, stream>>>(hist, offs, cur);
    scatter_nodes<<<(N_NODES + 255) / 256, 256, 0, stream>>>(frag_batch, remap, cur, node_list);
    gather_mean<<<F_FRAG / 4, 256, 0, stream>>>(out, remap, hist, offs, node_list, fmean);
    proj_kernel<<<D_DANG / 32, 512, 0, stream>>>(out, dangling_idx, frag_batch, remap,
                                                 W, b, fmean, h);
    combo_sort<<<1, 256, 0, stream>>>(attr, esorted, coffs);
    build_mc<<<dim3((EMB2 + 255) / 256, 9), 256, 0, stream>>>(emb1, emb2, Mc);
    edge_gemm<<<dim3((E_EDGE + 31) / 32, 9), 512, 0, stream>>>(h, Mc, eidx, esorted, coffs, o);
    fill_labels<<<(E_EDGE + 255) / 256, 256, 0, stream>>>(o);
}

// Round 5
// 159.267 us; speedup vs baseline: 2.8684x; 1.3595x over previous
//
#include <hip/hip_runtime.h>

#define N_NODES 100000
#define F_FRAG  16384
#define D_DANG  8192
#define E_EDGE  4096
#define EMB     300
#define EMB2    90000   // EMB*EMB
#define EMB4    75      // EMB/4
#define DCH     100     // d-chunk for edge gemm (3 chunks; 100 % 4 == 0, 400B-aligned)

// ---------------- init ----------------
__global__ void init_meta(int* hist, int* remap, int* n_needed) {
    int i = blockIdx.x * blockDim.x + threadIdx.x;
    if (i < F_FRAG) { hist[i] = 0; remap[i] = -1; }
    if (i == 0) *n_needed = 0;
}

__global__ void mark_needed(const int* __restrict__ dangling_idx,
                            const int* __restrict__ frag_batch,
                            int* __restrict__ remap, int* __restrict__ n_needed) {
    int i = blockIdx.x * blockDim.x + threadIdx.x;
    if (i >= D_DANG) return;
    int f = frag_batch[dangling_idx[i]];
    if (atomicCAS(&remap[f], -1, -2) == -1)
        remap[f] = atomicAdd(n_needed, 1);
}

// ---------------- counting sort of nodes by fragment ----------------
__global__ void node_hist(const int* __restrict__ frag_batch, int* __restrict__ hist) {
    int i = blockIdx.x * blockDim.x + threadIdx.x;
    if (i < N_NODES) atomicAdd(&hist[frag_batch[i]], 1);
}

__global__ __launch_bounds__(256) void scan_hist(const int* __restrict__ hist,
                                                 int* __restrict__ offs,
                                                 int* __restrict__ cur) {
    __shared__ int part[256];
    __shared__ int pref[257];
    int t = threadIdx.x;
    int base = t * 64;
    int s = 0;
    for (int j = 0; j < 64; ++j) s += hist[base + j];
    part[t] = s;
    __syncthreads();
    if (t == 0) {
        pref[0] = 0;
        for (int i = 0; i < 256; ++i) pref[i + 1] = pref[i] + part[i];
    }
    __syncthreads();
    int run = pref[t];
    for (int j = 0; j < 64; ++j) {
        offs[base + j] = run;
        cur[base + j]  = run;
        run += hist[base + j];
    }
}

__global__ void scatter_nodes(const int* __restrict__ frag_batch,
                              const int* __restrict__ remap,
                              int* __restrict__ cur, int* __restrict__ node_list) {
    int i = blockIdx.x * blockDim.x + threadIdx.x;
    if (i >= N_NODES) return;
    int f = frag_batch[i];
    if (remap[f] < 0) return;
    int p = atomicAdd(&cur[f], 1);
    node_list[p] = i;
}

// one wave per needed fragment, full 300-col row; writes MEAN (compacted)
__global__ __launch_bounds__(256) void gather_mean(
    const float* __restrict__ out, const int* __restrict__ remap,
    const int* __restrict__ hist, const int* __restrict__ offs,
    const int* __restrict__ node_list, float* __restrict__ fmean) {
    int wid = blockIdx.x * 4 + (threadIdx.x >> 6);
    if (wid >= F_FRAG) return;
    int cid = remap[wid];
    if (cid < 0) return;
    int lane = threadIdx.x & 63;
    int cnt = hist[wid], off = offs[wid];
    float acc[5] = {0.f, 0.f, 0.f, 0.f, 0.f};
    int n = 0;
    for (; n + 1 < cnt; n += 2) {
        const float* r0 = out + (size_t)node_list[off + n] * EMB;
        const float* r1 = out + (size_t)node_list[off + n + 1] * EMB;
#pragma unroll
        for (int j = 0; j < 5; ++j) {
            int k = lane + 64 * j;
            if (k < EMB) acc[j] += r0[k] + r1[k];
        }
    }
    if (n < cnt) {
        const float* r0 = out + (size_t)node_list[off + n] * EMB;
#pragma unroll
        for (int j = 0; j < 5; ++j) {
            int k = lane + 64 * j;
            if (k < EMB) acc[j] += r0[k];
        }
    }
    float inv = 1.0f / fmaxf((float)cnt, 1.0f);
#pragma unroll
    for (int j = 0; j < 5; ++j) {
        int k = lane + 64 * j;
        if (k < EMB) fmean[(size_t)cid * EMB + k] = acc[j] * inv;
    }
}

// ---------------- projection: h = out[didx] @ W + b + fmean ----------------
// 16 rows/block, 512 thr = 8 waves; thread: 2 rows x 5 cols (all 300)
__global__ __launch_bounds__(512) void proj_kernel(
    const float* __restrict__ out, const int* __restrict__ dangling_idx,
    const int* __restrict__ frag_batch, const int* __restrict__ remap,
    const float* __restrict__ W, const float* __restrict__ b,
    const float* __restrict__ fmean, float* __restrict__ h) {
    __shared__ float rows[16][EMB];
    __shared__ int gidx[16], cids[16];
    int base = blockIdx.x * 16;
    if (threadIdx.x < 16) {
        int gi = dangling_idx[base + threadIdx.x];
        gidx[threadIdx.x] = gi;
        cids[threadIdx.x] = remap[frag_batch[gi]];
    }
    __syncthreads();
    {
        float4* dst = (float4*)&rows[0][0];
        for (int j = threadIdx.x; j < 16 * EMB4; j += 512) {
            int r = j / EMB4, col = j - r * EMB4;
            dst[j] = ((const float4*)(out + (size_t)gidx[r] * EMB))[col];
        }
    }
    __syncthreads();
    int lane = threadIdx.x & 63;
    int wv   = threadIdx.x >> 6;
    bool k4ok = (lane + 256 < EMB);
    float acc[2][5];
#pragma unroll
    for (int i = 0; i < 2; ++i)
#pragma unroll
        for (int j = 0; j < 5; ++j) acc[i][j] = 0.f;

    for (int d = 0; d < EMB; d += 4) {
        float w[4][5];
#pragma unroll
        for (int t = 0; t < 4; ++t) {
            const float* Wr = W + (size_t)(d + t) * EMB + lane;
#pragma unroll
            for (int j = 0; j < 5; ++j)
                w[t][j] = (j < 4 || k4ok) ? Wr[64 * j] : 0.f;
        }
#pragma unroll
        for (int i = 0; i < 2; ++i) {
            float4 hv = *(const float4*)&rows[wv * 2 + i][d];
#pragma unroll
            for (int j = 0; j < 5; ++j)
                acc[i][j] += hv.x * w[0][j] + hv.y * w[1][j] +
                             hv.z * w[2][j] + hv.w * w[3][j];
        }
    }
#pragma unroll
    for (int i = 0; i < 2; ++i) {
        int li = wv * 2 + i;
        float* hr = h + (size_t)(base + li) * EMB;
        const float* fm = fmean + (size_t)cids[li] * EMB;
#pragma unroll
        for (int j = 0; j < 5; ++j) {
            int k = lane + 64 * j;
            if (j < 4 || k4ok)
                hr[k] = acc[i][j] + b[k] + fm[k];
        }
    }
}

// ---------------- merged edge sort by (a0,a1) combo (9 bins) ----------------
__global__ __launch_bounds__(256) void combo_sort(const int* __restrict__ attr,
                                                  int* __restrict__ esorted,
                                                  int* __restrict__ coffs) {
    __shared__ int sh[9], scur[9];
    int t = threadIdx.x;
    if (t < 9) sh[t] = 0;
    __syncthreads();
    for (int e = t; e < E_EDGE; e += 256)
        atomicAdd(&sh[attr[e * 2] * 3 + attr[e * 2 + 1]], 1);
    __syncthreads();
    if (t == 0) {
        int run = 0;
        for (int c = 0; c < 9; ++c) { scur[c] = run; coffs[c] = run; run += sh[c]; }
        coffs[9] = run;
    }
    __syncthreads();
    for (int e = t; e < E_EDGE; e += 256) {
        int c = attr[e * 2] * 3 + attr[e * 2 + 1];
        int p = atomicAdd(&scur[c], 1);
        esorted[p] = e;
    }
}

// Mc[c] = emb1[c/3] + emb2[c%3]
__global__ void build_mc(const float* __restrict__ emb1, const float* __restrict__ emb2,
                         float* __restrict__ Mc) {
    int c = blockIdx.y;
    int i = blockIdx.x * blockDim.x + threadIdx.x;
    if (i < EMB2)
        Mc[(size_t)c * EMB2 + i] = emb1[(size_t)(c / 3) * EMB2 + i] +
                                   emb2[(size_t)(c % 3) * EMB2 + i];
}

// zero logits (atomic targets) + write constant labels; runs before edge_gemm
__global__ void init_out(float* __restrict__ outp) {
    int i = blockIdx.x * blockDim.x + threadIdx.x;
    if (i < 4 * E_EDGE)
        outp[i] = (i < 2 * E_EDGE) ? 0.f : ((i < 3 * E_EDGE) ? 1.f : 0.f);
}

// ---------------- per-combo fused edge GEMM + partial dots, d-split x3 ----------------
// grid (tile, dchunk, combo); 16 edges/block, 512 thr; thread: 2 edges x 5 cols
__global__ __launch_bounds__(512) void edge_gemm(
    const float* __restrict__ h, const float* __restrict__ Mc,
    const int* __restrict__ eidx, const int* __restrict__ esorted,
    const int* __restrict__ coffs, float* __restrict__ outp) {
    int c     = blockIdx.z;
    int start = coffs[c] + blockIdx.x * 16;
    int end   = coffs[c + 1];
    if (start >= end) return;
    int ne  = min(16, end - start);
    int dlo = blockIdx.y * DCH;

    __shared__ float hs[16][104];   // 104 pad: 416B rows keep b128 16B-aligned
    __shared__ int eids[16], srcs[16], dsts[16], dsts2[16];
    if (threadIdx.x < 16) {
        int li = threadIdx.x;
        int eo = esorted[start + ((li < ne) ? li : 0)];
        eids[li] = eo;
        srcs[li] = eidx[eo];
        dsts[li] = eidx[E_EDGE + eo];
        int ep   = (eo == 0) ? (E_EDGE - 1) : (eo - 1);
        dsts2[li] = eidx[E_EDGE + ep];
    }
    __syncthreads();
    for (int j = threadIdx.x; j < 16 * (DCH / 4); j += 512) {
        int r = j / (DCH / 4), col = j - r * (DCH / 4);
        *(float4*)&hs[r][col * 4] =
            ((const float4*)(h + (size_t)srcs[r] * EMB + dlo))[col];
    }
    __syncthreads();

    int lane = threadIdx.x & 63;
    int wv   = threadIdx.x >> 6;
    bool k4ok = (lane + 256 < EMB);
    const float* M = Mc + (size_t)c * EMB2 + (size_t)dlo * EMB;
    float acc[2][5];
#pragma unroll
    for (int i = 0; i < 2; ++i)
#pragma unroll
        for (int j = 0; j < 5; ++j) acc[i][j] = 0.f;

    for (int d = 0; d < DCH; d += 4) {
        float w[4][5];
#pragma unroll
        for (int t = 0; t < 4; ++t) {
            const float* Mr = M + (size_t)(d + t) * EMB + lane;
#pragma unroll
            for (int j = 0; j < 5; ++j)
                w[t][j] = (j < 4 || k4ok) ? Mr[64 * j] : 0.f;
        }
#pragma unroll
        for (int i = 0; i < 2; ++i) {
            float4 hv = *(const float4*)&hs[wv * 2 + i][d];
#pragma unroll
            for (int j = 0; j < 5; ++j)
                acc[i][j] += hv.x * w[0][j] + hv.y * w[1][j] +
                             hv.z * w[2][j] + hv.w * w[3][j];
        }
    }

    // partial dots over this d-chunk's partial v
    float p1[2], p2[2];
#pragma unroll
    for (int i = 0; i < 2; ++i) {
        int li = wv * 2 + i;
        const float* h1 = h + (size_t)dsts[li]  * EMB + lane;
        const float* h2 = h + (size_t)dsts2[li] * EMB + lane;
        float s1 = 0.f, s2 = 0.f;
#pragma unroll
        for (int j = 0; j < 5; ++j) {
            if (j < 4 || k4ok) {
                float a = acc[i][j];
                s1 += a * h1[64 * j];
                s2 += a * h2[64 * j];
            }
        }
        p1[i] = s1; p2[i] = s2;
    }
#pragma unroll
    for (int off = 32; off; off >>= 1) {
#pragma unroll
        for (int i = 0; i < 2; ++i) {
            p1[i] += __shfl_down(p1[i], off);
            p2[i] += __shfl_down(p2[i], off);
        }
    }
    if (lane == 0) {
#pragma unroll
        for (int i = 0; i < 2; ++i) {
            int li = wv * 2 + i;
            if (li < ne) {
                int eo = eids[li];
                atomicAdd(&outp[eo],          p1[i]);
                atomicAdd(&outp[E_EDGE + eo], p2[i]);
            }
        }
    }
}

extern "C" void kernel_launch(void* const* d_in, const int* in_sizes, int n_in,
                              void* d_out, int out_size, void* d_ws, size_t ws_size,
                              hipStream_t stream) {
    const float* out          = (const float*)d_in[0];
    const int*   frag_batch   = (const int*)d_in[1];
    const int*   dangling_idx = (const int*)d_in[2];
    const int*   eidx         = (const int*)d_in[3];
    const int*   attr         = (const int*)d_in[4];
    const float* W            = (const float*)d_in[5];
    const float* b            = (const float*)d_in[6];
    const float* emb1         = (const float*)d_in[7];
    const float* emb2         = (const float*)d_in[8];
    float* o  = (float*)d_out;

    char* p = (char*)d_ws;
    auto alloc = [&](size_t bytes) {
        char* r = p;
        p += (bytes + 255) & ~(size_t)255;
        return (void*)r;
    };
    float* fmean     = (float*)alloc((size_t)D_DANG * EMB * 4); // compacted means
    float* h         = (float*)alloc((size_t)D_DANG * EMB * 4);
    float* Mc        = (float*)alloc((size_t)9 * EMB2 * 4);
    int*   hist      = (int*)alloc(F_FRAG * 4);
    int*   offs      = (int*)alloc(F_FRAG * 4);
    int*   cur       = (int*)alloc(F_FRAG * 4);
    int*   remap     = (int*)alloc(F_FRAG * 4);
    int*   node_list = (int*)alloc(N_NODES * 4);
    int*   esorted   = (int*)alloc(E_EDGE * 4);
    int*   coffs     = (int*)alloc(16 * 4);
    int*   n_needed  = (int*)alloc(4);

    init_meta<<<F_FRAG / 256, 256, 0, stream>>>(hist, remap, n_needed);
    mark_needed<<<D_DANG / 256, 256, 0, stream>>>(dangling_idx, frag_batch, remap, n_needed);
    node_hist<<<(N_NODES + 255) / 256, 256, 0, stream>>>(frag_batch, hist);
    scan_hist<<<1, 256, 0, stream>>>(hist, offs, cur);
    scatter_nodes<<<(N_NODES + 255) / 256, 256, 0, stream>>>(frag_batch, remap, cur, node_list);
    gather_mean<<<F_FRAG / 4, 256, 0, stream>>>(out, remap, hist, offs, node_list, fmean);
    proj_kernel<<<D_DANG / 16, 512, 0, stream>>>(out, dangling_idx, frag_batch, remap,
                                                 W, b, fmean, h);
    combo_sort<<<1, 256, 0, stream>>>(attr, esorted, coffs);
    build_mc<<<dim3((EMB2 + 255) / 256, 9), 256, 0, stream>>>(emb1, emb2, Mc);
    init_out<<<(4 * E_EDGE + 255) / 256, 256, 0, stream>>>(o);
    // 64 tiles x 16 = 1024-edge capacity per combo (mean 455, sigma ~20 — safe);
    // empty tiles early-exit on the coffs check.
    edge_gemm<<<dim3(64, 3, 9), 512, 0, stream>>>(h, Mc, eidx, esorted, coffs, o);
}